// Round 2
// baseline (722.793 us; speedup 1.0000x reference)
//
#include <hip/hip_runtime.h>
#include <float.h>

#define NN 5000
#define NE 50000
#define C 64
#define CHW4 768       // 64*12*4 / 4
#define SPLIT 25
#define NPS 200        // 5000/25
#define MAXD 64

// ---------------- CSR build ----------------
__global__ void hist_kernel(const int* __restrict__ dst, int* __restrict__ cnt) {
  int e = blockIdx.x * 256 + threadIdx.x;
  if (e < NE) atomicAdd(&cnt[dst[e]], 1);
}

__global__ void scan_kernel(const int* __restrict__ cnt, int* __restrict__ off, int* __restrict__ cur) {
  __shared__ int tsum[256];
  int t = threadIdx.x;
  constexpr int PER = 20;
  int base = t * PER;
  int vals[PER];
  int local = 0;
#pragma unroll
  for (int i = 0; i < PER; i++) {
    int idx = base + i;
    int v = (idx < NN) ? cnt[idx] : 0;
    vals[i] = local;
    local += v;
  }
  tsum[t] = local;
  __syncthreads();
  for (int o = 1; o < 256; o <<= 1) {
    int v = (t >= o) ? tsum[t - o] : 0;
    __syncthreads();
    tsum[t] += v;
    __syncthreads();
  }
  int excl = (t == 0) ? 0 : tsum[t - 1];
#pragma unroll
  for (int i = 0; i < PER; i++) {
    int idx = base + i;
    if (idx < NN) {
      int o2 = excl + vals[i];
      off[idx] = o2;
      cur[idx] = o2;
    }
  }
  if (t == 255) off[NN] = excl + local;
}

__global__ void scatter_kernel(const int* __restrict__ dst, const int* __restrict__ src,
                               int* __restrict__ cur, int* __restrict__ eids, int* __restrict__ srcs) {
  int e = blockIdx.x * 256 + threadIdx.x;
  if (e < NE) {
    int p = atomicAdd(&cur[dst[e]], 1);
    eids[p] = e;
    srcs[p] = src[e];
  }
}

// ---------------- BatchNorm stats (layer 0 only) ----------------
__global__ void bn_stats_kernel(const float* __restrict__ hv, float* __restrict__ statsN) {
  int c = blockIdx.x / SPLIT, s = blockIdx.x % SPLIT;
  int n0 = s * NPS;
  const float4* hv4 = (const float4*)hv;
  float sum = 0.f, ss = 0.f;
  for (int i = threadIdx.x; i < NPS * 12; i += 256) {
    int n = n0 + i / 12, p = i % 12;
    float4 v = hv4[(size_t)n * CHW4 + c * 12 + p];
    sum += v.x + v.y + v.z + v.w;
    ss += v.x * v.x + v.y * v.y + v.z * v.z + v.w * v.w;
  }
  __shared__ float rs[256], rq[256];
  rs[threadIdx.x] = sum;
  rq[threadIdx.x] = ss;
  __syncthreads();
  for (int o = 128; o > 0; o >>= 1) {
    if (threadIdx.x < o) {
      rs[threadIdx.x] += rs[threadIdx.x + o];
      rq[threadIdx.x] += rq[threadIdx.x + o];
    }
    __syncthreads();
  }
  if (threadIdx.x == 0) {
    int r = blockIdx.x & 7;
    atomicAdd(&statsN[r * 128 + c], rs[0]);
    atomicAdd(&statsN[r * 128 + 64 + c], rq[0]);
  }
}

__global__ void finalize2_kernel(const float* __restrict__ statsN, const float* __restrict__ gamma,
                                 const float* __restrict__ beta, float* __restrict__ sc,
                                 float* __restrict__ sh) {
  int c = threadIdx.x;
  if (c < C) {
    float s = 0.f, q = 0.f;
#pragma unroll
    for (int r = 0; r < 8; r++) {
      s += statsN[r * 128 + c];
      q += statsN[r * 128 + 64 + c];
    }
    const float inv = 1.f / 240000.f;
    float mu = s * inv;
    float var = q * inv - mu * mu;
    float scale = gamma[c] * rsqrtf(var + 1e-5f);
    sc[c] = scale;
    sh[c] = beta[c] - mu * scale;
  }
}

// ---------------- Fused GENConv layer ----------------
// One block per node. Fused: BN+ReLU inline, online-softmax edge aggregation,
// 64x64 channel linear (register-tiled 4-out-channel chunks), residual,
// next-layer BN stats; for LAST layer: fused pooled output projection.
template <bool LAST>
__global__ __launch_bounds__(256) void aggregate_kernel(
    const float* __restrict__ hv, const float* __restrict__ he,
    const int* __restrict__ srcs, const int* __restrict__ eids, const int* __restrict__ off,
    const float* __restrict__ Wg, const float* __restrict__ bg,
    const float* __restrict__ sc, const float* __restrict__ sh,
    float* __restrict__ hvNext, float* __restrict__ statsNext,
    const float* __restrict__ oW, const float* __restrict__ ob,
    float* __restrict__ out) {
  __shared__ float Wl[4096];
  __shared__ float fl[3072];
  __shared__ float scl[64], shl[64];
  __shared__ int sE[MAXD], sS[MAXD];
  __shared__ float bsum[64], bsq[64];

  int n = blockIdx.x, t = threadIdx.x;
  for (int i = t; i < 4096; i += 256) Wl[i] = Wg[i];
  if (t < 64) {
    scl[t] = sc[t];
    shl[t] = sh[t];
    bsum[t] = 0.f;
    bsq[t] = 0.f;
  }
  __syncthreads();

  const float4* hv4 = (const float4*)hv;
  const float4* he4 = (const float4*)he;

  float scv[3], shv[3], h1[12];
#pragma unroll
  for (int j = 0; j < 3; j++) {
    int q = t + j * 256;
    int c = q / 12;
    scv[j] = scl[c];
    shv[j] = shl[c];
    float4 v = hv4[(size_t)n * CHW4 + q];
    h1[4 * j + 0] = fmaxf(v.x * scv[j] + shv[j], 0.f);
    h1[4 * j + 1] = fmaxf(v.y * scv[j] + shv[j], 0.f);
    h1[4 * j + 2] = fmaxf(v.z * scv[j] + shv[j], 0.f);
    h1[4 * j + 3] = fmaxf(v.w * scv[j] + shv[j], 0.f);
  }

  float M[12], S[12], T[12];
#pragma unroll
  for (int i = 0; i < 12; i++) {
    M[i] = -FLT_MAX;
    S[i] = 0.f;
    T[i] = 0.f;
  }

  int e0 = off[n], d = off[n + 1] - e0;
  for (int base = 0; base < d; base += MAXD) {
    int cnt = min(MAXD, d - base);
    __syncthreads();
    if (t < cnt) {
      sE[t] = eids[e0 + base + t];
      sS[t] = srcs[e0 + base + t];
    }
    __syncthreads();
#pragma unroll 2
    for (int k = 0; k < cnt; k++) {
      size_t hb = (size_t)sS[k] * CHW4, eb = (size_t)sE[k] * CHW4;
#pragma unroll
      for (int j = 0; j < 3; j++) {
        int q = t + j * 256;
        float4 a = hv4[hb + q];
        float4 b = he4[eb + q];
        float av[4] = {a.x, a.y, a.z, a.w};
        float bv[4] = {b.x, b.y, b.z, b.w};
#pragma unroll
        for (int u = 0; u < 4; u++) {
          float x = fmaxf(av[u] * scv[j] + shv[j], 0.f);
          float m = fmaxf(x + bv[u], 0.f) + 1e-7f;
          int idx = j * 4 + u;
          float nM = fmaxf(M[idx], m);
          float f1 = __expf(M[idx] - nM);
          float f2 = __expf(m - nM);
          S[idx] = S[idx] * f1 + f2;
          T[idx] = T[idx] * f1 + f2 * m;
          M[idx] = nM;
        }
      }
    }
  }

  bool hasE = d > 0;
  float4* fl4 = (float4*)fl;
#pragma unroll
  for (int j = 0; j < 3; j++) {
    int q = t + j * 256, idx = 4 * j;
    float4 f;
    f.x = h1[idx + 0] + (hasE ? T[idx + 0] / S[idx + 0] : 0.f);
    f.y = h1[idx + 1] + (hasE ? T[idx + 1] / S[idx + 1] : 0.f);
    f.z = h1[idx + 2] + (hasE ? T[idx + 2] / S[idx + 2] : 0.f);
    f.w = h1[idx + 3] + (hasE ? T[idx + 3] / S[idx + 3] : 0.f);
    fl4[q] = f;
  }
  __syncthreads();

  // linear: 192 threads, each owns 4 consecutive out-channels x one h position
  int o0 = (t / 12) * 4, hbp = t % 12;
  float4 acc[4];
  if (t < 192) {
#pragma unroll
    for (int i = 0; i < 4; i++) {
      float bv = bg[o0 + i];
      acc[i] = make_float4(bv, bv, bv, bv);
    }
    const float4* w4 = (const float4*)Wl;
    int widx = o0 >> 2;
    for (int c2 = 0; c2 < 64; c2++) {
      float4 fv = fl4[c2 * 12 + hbp];
      float4 wv = w4[c2 * 16 + widx];
      acc[0].x += wv.x * fv.x; acc[0].y += wv.x * fv.y; acc[0].z += wv.x * fv.z; acc[0].w += wv.x * fv.w;
      acc[1].x += wv.y * fv.x; acc[1].y += wv.y * fv.y; acc[1].z += wv.y * fv.z; acc[1].w += wv.y * fv.w;
      acc[2].x += wv.z * fv.x; acc[2].y += wv.z * fv.y; acc[2].z += wv.z * fv.z; acc[2].w += wv.z * fv.w;
      acc[3].x += wv.w * fv.x; acc[3].y += wv.w * fv.y; acc[3].z += wv.w * fv.z; acc[3].w += wv.w * fv.w;
    }
    // residual (hv fully L3-resident)
#pragma unroll
    for (int i = 0; i < 4; i++) {
      float4 r = hv4[(size_t)n * CHW4 + (o0 + i) * 12 + hbp];
      acc[i].x += r.x; acc[i].y += r.y; acc[i].z += r.z; acc[i].w += r.w;
    }
  }

  if constexpr (!LAST) {
    if (t < 192) {
      float4* hn4 = (float4*)hvNext;
#pragma unroll
      for (int i = 0; i < 4; i++) {
        hn4[(size_t)n * CHW4 + (o0 + i) * 12 + hbp] = acc[i];
        float s4 = acc[i].x + acc[i].y + acc[i].z + acc[i].w;
        float q4 = acc[i].x * acc[i].x + acc[i].y * acc[i].y + acc[i].z * acc[i].z + acc[i].w * acc[i].w;
        atomicAdd(&bsum[o0 + i], s4);
        atomicAdd(&bsq[o0 + i], q4);
      }
    }
    __syncthreads();
    int r = n & 7;
    if (t < 64) atomicAdd(&statsNext[r * 128 + t], bsum[t]);
    else if (t < 128) atomicAdd(&statsNext[r * 128 + 64 + (t - 64)], bsq[t - 64]);
  } else {
    // fused output projection: h_g = mean_w(hv)*hv; out = einsum(h_g, oW) + ob
    __syncthreads();  // everyone done reading fl/Wl from the linear
    if (t < 192) {
#pragma unroll
      for (int i = 0; i < 4; i++) fl4[(o0 + i) * 12 + hbp] = acc[i];
    }
    for (int i = t; i < 768; i += 256) Wl[i] = oW[i];  // Wl[0:768] = oW
    __syncthreads();
    for (int i = t; i < 768; i += 256) {
      float4 v = fl4[i];
      Wl[1024 + i] = (v.x + v.y + v.z + v.w) * 0.25f;  // Wl[1024:1792] = mean over W
    }
    __syncthreads();
    if (t < 144) {
      int o = t / 12, hb = t % 12;
      float bias = ob[o];
      float4 a = make_float4(bias, bias, bias, bias);
      for (int c2 = 0; c2 < 64; c2++) {
        float4 v = fl4[c2 * 12 + hb];
        float wv = Wl[c2 * 12 + o] * Wl[1024 + c2 * 12 + hb];
        a.x += wv * v.x; a.y += wv * v.y; a.z += wv * v.z; a.w += wv * v.w;
      }
      ((float4*)out)[(size_t)n * 144 + t] = a;
    }
  }
}

extern "C" void kernel_launch(void* const* d_in, const int* in_sizes, int n_in,
                              void* d_out, int out_size, void* d_ws, size_t ws_size,
                              hipStream_t stream) {
  const float* node_feats = (const float*)d_in[0];
  const float* edge_feats = (const float*)d_in[1];
  const int* src = (const int*)d_in[2];
  const int* dst = (const int*)d_in[3];
  const float* bn_gamma = (const float*)d_in[4];
  const float* bn_beta = (const float*)d_in[5];
  const float* gen_W = (const float*)d_in[6];
  const float* gen_b = (const float*)d_in[7];
  const float* out_W = (const float*)d_in[8];
  const float* out_b = (const float*)d_in[9];
  float* out = (float*)d_out;

  char* ws = (char*)d_ws;
  float* hvA = (float*)ws;                      // 61,440,000 B
  float* hvB = (float*)(ws + 61440000);         // 61,440,000 B
  float* statsN = (float*)(ws + 122880000);     // 4096 B (8 replicas x 128)
  float* sc = (float*)(ws + 122884096);         // 256 B
  float* sh = (float*)(ws + 122884352);         // 256 B
  int* cnt = (int*)(ws + 122884608);            // 20,000 B
  int* off = (int*)(ws + 122904608);            // 20,004 B
  int* cur = (int*)(ws + 122924612);            // 20,000 B
  int* eids = (int*)(ws + 122944612);           // 200,000 B
  int* srcs = (int*)(ws + 123144612);           // 200,000 B

  // CSR build (dst -> edge list, with pre-resolved src per slot)
  hipMemsetAsync(cnt, 0, NN * sizeof(int), stream);
  hist_kernel<<<(NE + 255) / 256, 256, 0, stream>>>(dst, cnt);
  scan_kernel<<<1, 256, 0, stream>>>(cnt, off, cur);
  scatter_kernel<<<(NE + 255) / 256, 256, 0, stream>>>(dst, src, cur, eids, srcs);

  // layer-0 BN stats
  hipMemsetAsync(statsN, 0, 1024 * sizeof(float), stream);
  bn_stats_kernel<<<C * SPLIT, 256, 0, stream>>>(node_feats, statsN);

  const float* hvPrev = node_feats;
  float* bufs[2] = {hvA, hvB};
  for (int l = 0; l < 3; l++) {
    finalize2_kernel<<<1, 64, 0, stream>>>(statsN, bn_gamma + l * C, bn_beta + l * C, sc, sh);
    if (l < 2) {
      hipMemsetAsync(statsN, 0, 1024 * sizeof(float), stream);
      float* hvNext = bufs[l & 1];
      aggregate_kernel<false><<<NN, 256, 0, stream>>>(
          hvPrev, edge_feats, srcs, eids, off, gen_W + l * C * C, gen_b + l * C,
          sc, sh, hvNext, statsN, out_W, out_b, out);
      hvPrev = hvNext;
    } else {
      aggregate_kernel<true><<<NN, 256, 0, stream>>>(
          hvPrev, edge_feats, srcs, eids, off, gen_W + l * C * C, gen_b + l * C,
          sc, sh, hvA, statsN, out_W, out_b, out);
    }
  }
}

// Round 3
// 631.732 us; speedup vs baseline: 1.1441x; 1.1441x over previous
//
#include <hip/hip_runtime.h>
#include <float.h>

#define NN 5000
#define NE 50000
#define C 64
#define CHW4 768       // 64*12*4 / 4
#define SPLIT 25
#define NPS 200        // 5000/25
#define MAXD 64

typedef float f32x4 __attribute__((ext_vector_type(4)));

// ---------------- CSR build ----------------
__global__ void hist_kernel(const int* __restrict__ dst, int* __restrict__ cnt) {
  int e = blockIdx.x * 256 + threadIdx.x;
  if (e < NE) atomicAdd(&cnt[dst[e]], 1);
}

__global__ void scan_kernel(const int* __restrict__ cnt, int* __restrict__ off, int* __restrict__ cur) {
  __shared__ int tsum[256];
  int t = threadIdx.x;
  constexpr int PER = 20;
  int base = t * PER;
  int vals[PER];
  int local = 0;
#pragma unroll
  for (int i = 0; i < PER; i++) {
    int idx = base + i;
    int v = (idx < NN) ? cnt[idx] : 0;
    vals[i] = local;
    local += v;
  }
  tsum[t] = local;
  __syncthreads();
  for (int o = 1; o < 256; o <<= 1) {
    int v = (t >= o) ? tsum[t - o] : 0;
    __syncthreads();
    tsum[t] += v;
    __syncthreads();
  }
  int excl = (t == 0) ? 0 : tsum[t - 1];
#pragma unroll
  for (int i = 0; i < PER; i++) {
    int idx = base + i;
    if (idx < NN) {
      int o2 = excl + vals[i];
      off[idx] = o2;
      cur[idx] = o2;
    }
  }
  if (t == 255) off[NN] = excl + local;
}

__global__ void scatter_kernel(const int* __restrict__ dst, const int* __restrict__ src,
                               int* __restrict__ cur, int* __restrict__ eids, int* __restrict__ srcs) {
  int e = blockIdx.x * 256 + threadIdx.x;
  if (e < NE) {
    int p = atomicAdd(&cur[dst[e]], 1);
    eids[p] = e;
    srcs[p] = src[e];
  }
}

// ---------------- BatchNorm stats (layer 0 only) ----------------
__global__ void bn_stats_kernel(const float* __restrict__ hv, float* __restrict__ statsN) {
  int c = blockIdx.x / SPLIT, s = blockIdx.x % SPLIT;
  int n0 = s * NPS;
  const float4* hv4 = (const float4*)hv;
  float sum = 0.f, ss = 0.f;
  for (int i = threadIdx.x; i < NPS * 12; i += 256) {
    int n = n0 + i / 12, p = i % 12;
    float4 v = hv4[(size_t)n * CHW4 + c * 12 + p];
    sum += v.x + v.y + v.z + v.w;
    ss += v.x * v.x + v.y * v.y + v.z * v.z + v.w * v.w;
  }
  __shared__ float rs[256], rq[256];
  rs[threadIdx.x] = sum;
  rq[threadIdx.x] = ss;
  __syncthreads();
  for (int o = 128; o > 0; o >>= 1) {
    if (threadIdx.x < o) {
      rs[threadIdx.x] += rs[threadIdx.x + o];
      rq[threadIdx.x] += rq[threadIdx.x + o];
    }
    __syncthreads();
  }
  if (threadIdx.x == 0) {
    int r = blockIdx.x & 7;
    atomicAdd(&statsN[r * 128 + c], rs[0]);
    atomicAdd(&statsN[r * 128 + 64 + c], rq[0]);
  }
}

__global__ void finalize2_kernel(const float* __restrict__ statsN, const float* __restrict__ gamma,
                                 const float* __restrict__ beta, float* __restrict__ sc,
                                 float* __restrict__ sh) {
  int c = threadIdx.x;
  if (c < C) {
    float s = 0.f, q = 0.f;
#pragma unroll
    for (int r = 0; r < 8; r++) {
      s += statsN[r * 128 + c];
      q += statsN[r * 128 + 64 + c];
    }
    const float inv = 1.f / 240000.f;
    float mu = s * inv;
    float var = q * inv - mu * mu;
    float scale = gamma[c] * rsqrtf(var + 1e-5f);
    sc[c] = scale;
    sh[c] = beta[c] - mu * scale;
  }
}

// ---------------- Fused GENConv layer ----------------
template <bool LAST>
__global__ __launch_bounds__(256) void aggregate_kernel(
    const float* __restrict__ hv, const float* __restrict__ he,
    const int* __restrict__ srcs, const int* __restrict__ eids, const int* __restrict__ off,
    const float* __restrict__ Wg, const float* __restrict__ bg,
    const float* __restrict__ sc, const float* __restrict__ sh,
    float* __restrict__ hvNext, float* __restrict__ statsNext,
    const float* __restrict__ oW, const float* __restrict__ ob,
    float* __restrict__ out) {
  __shared__ float Wl[4096];
  __shared__ float fl[3072];
  __shared__ float scl[64], shl[64];
  __shared__ int sE[MAXD], sS[MAXD];
  __shared__ float bsum[64], bsq[64];

  int n = blockIdx.x, t = threadIdx.x;
  for (int i = t; i < 4096; i += 256) Wl[i] = Wg[i];
  if (t < 64) {
    scl[t] = sc[t];
    shl[t] = sh[t];
    bsum[t] = 0.f;
    bsq[t] = 0.f;
  }
  __syncthreads();

  const float4* hv4 = (const float4*)hv;
  const f32x4* heV = (const f32x4*)he;

  float scv[3], shv[3], h1[12];
#pragma unroll
  for (int j = 0; j < 3; j++) {
    int q = t + j * 256;
    int c = q / 12;
    scv[j] = scl[c];
    shv[j] = shl[c];
    float4 v = hv4[(size_t)n * CHW4 + q];
    h1[4 * j + 0] = fmaxf(v.x * scv[j] + shv[j], 0.f);
    h1[4 * j + 1] = fmaxf(v.y * scv[j] + shv[j], 0.f);
    h1[4 * j + 2] = fmaxf(v.z * scv[j] + shv[j], 0.f);
    h1[4 * j + 3] = fmaxf(v.w * scv[j] + shv[j], 0.f);
  }

  float M[12], S[12], T[12];
#pragma unroll
  for (int i = 0; i < 12; i++) {
    M[i] = -FLT_MAX;
    S[i] = 0.f;
    T[i] = 0.f;
  }

  int e0 = off[n], d = off[n + 1] - e0;
  for (int base = 0; base < d; base += MAXD) {
    int cnt = min(MAXD, d - base);
    __syncthreads();
    if (t < cnt) {
      sE[t] = eids[e0 + base + t];
      sS[t] = srcs[e0 + base + t];
    }
    __syncthreads();
#pragma unroll 2
    for (int k = 0; k < cnt; k++) {
      size_t hb = (size_t)sS[k] * CHW4, eb = (size_t)sE[k] * CHW4;
#pragma unroll
      for (int j = 0; j < 3; j++) {
        int q = t + j * 256;
        float4 a = hv4[hb + q];
        f32x4 b = __builtin_nontemporal_load(&heV[eb + q]);   // read-once stream: keep out of L3
        float av[4] = {a.x, a.y, a.z, a.w};
        float bv[4] = {b.x, b.y, b.z, b.w};
#pragma unroll
        for (int u = 0; u < 4; u++) {
          float x = fmaxf(av[u] * scv[j] + shv[j], 0.f);
          float m = fmaxf(x + bv[u], 0.f) + 1e-7f;
          int idx = j * 4 + u;
          // online softmax, single exp: one of the two factors is always exp(0)=1
          float dd = m - M[idx];
          float ed = __expf(-fabsf(dd));
          float f1 = dd > 0.f ? ed : 1.f;
          float f2 = dd > 0.f ? 1.f : ed;
          S[idx] = S[idx] * f1 + f2;
          T[idx] = T[idx] * f1 + f2 * m;
          M[idx] = fmaxf(M[idx], m);
        }
      }
    }
  }

  bool hasE = d > 0;
  float4* fl4 = (float4*)fl;
#pragma unroll
  for (int j = 0; j < 3; j++) {
    int q = t + j * 256, idx = 4 * j;
    float4 f;
    f.x = h1[idx + 0] + (hasE ? T[idx + 0] / S[idx + 0] : 0.f);
    f.y = h1[idx + 1] + (hasE ? T[idx + 1] / S[idx + 1] : 0.f);
    f.z = h1[idx + 2] + (hasE ? T[idx + 2] / S[idx + 2] : 0.f);
    f.w = h1[idx + 3] + (hasE ? T[idx + 3] / S[idx + 3] : 0.f);
    fl4[q] = f;
  }
  __syncthreads();

  // linear: 192 threads, each owns 4 consecutive out-channels x one h position
  int o0 = (t / 12) * 4, hbp = t % 12;
  float4 acc[4];
  if (t < 192) {
#pragma unroll
    for (int i = 0; i < 4; i++) {
      float bv = bg[o0 + i];
      acc[i] = make_float4(bv, bv, bv, bv);
    }
    const float4* w4 = (const float4*)Wl;
    int widx = o0 >> 2;
    for (int c2 = 0; c2 < 64; c2++) {
      float4 fv = fl4[c2 * 12 + hbp];
      float4 wv = w4[c2 * 16 + widx];
      acc[0].x += wv.x * fv.x; acc[0].y += wv.x * fv.y; acc[0].z += wv.x * fv.z; acc[0].w += wv.x * fv.w;
      acc[1].x += wv.y * fv.x; acc[1].y += wv.y * fv.y; acc[1].z += wv.y * fv.z; acc[1].w += wv.y * fv.w;
      acc[2].x += wv.z * fv.x; acc[2].y += wv.z * fv.y; acc[2].z += wv.z * fv.z; acc[2].w += wv.z * fv.w;
      acc[3].x += wv.w * fv.x; acc[3].y += wv.w * fv.y; acc[3].z += wv.w * fv.z; acc[3].w += wv.w * fv.w;
    }
#pragma unroll
    for (int i = 0; i < 4; i++) {
      float4 r = hv4[(size_t)n * CHW4 + (o0 + i) * 12 + hbp];
      acc[i].x += r.x; acc[i].y += r.y; acc[i].z += r.z; acc[i].w += r.w;
    }
  }

  if constexpr (!LAST) {
    if (t < 192) {
      float4* hn4 = (float4*)hvNext;
#pragma unroll
      for (int i = 0; i < 4; i++) {
        hn4[(size_t)n * CHW4 + (o0 + i) * 12 + hbp] = acc[i];
        float s4 = acc[i].x + acc[i].y + acc[i].z + acc[i].w;
        float q4 = acc[i].x * acc[i].x + acc[i].y * acc[i].y + acc[i].z * acc[i].z + acc[i].w * acc[i].w;
        atomicAdd(&bsum[o0 + i], s4);
        atomicAdd(&bsq[o0 + i], q4);
      }
    }
    __syncthreads();
    int r = n & 7;
    if (t < 64) atomicAdd(&statsNext[r * 128 + t], bsum[t]);
    else if (t < 128) atomicAdd(&statsNext[r * 128 + 64 + (t - 64)], bsq[t - 64]);
  } else {
    __syncthreads();
    if (t < 192) {
#pragma unroll
      for (int i = 0; i < 4; i++) fl4[(o0 + i) * 12 + hbp] = acc[i];
    }
    for (int i = t; i < 768; i += 256) Wl[i] = oW[i];
    __syncthreads();
    for (int i = t; i < 768; i += 256) {
      float4 v = fl4[i];
      Wl[1024 + i] = (v.x + v.y + v.z + v.w) * 0.25f;
    }
    __syncthreads();
    if (t < 144) {
      int o = t / 12, hb = t % 12;
      float bias = ob[o];
      float4 a = make_float4(bias, bias, bias, bias);
      for (int c2 = 0; c2 < 64; c2++) {
        float4 v = fl4[c2 * 12 + hb];
        float wv = Wl[c2 * 12 + o] * Wl[1024 + c2 * 12 + hb];
        a.x += wv * v.x; a.y += wv * v.y; a.z += wv * v.z; a.w += wv * v.w;
      }
      ((float4*)out)[(size_t)n * 144 + t] = a;
    }
  }
}

extern "C" void kernel_launch(void* const* d_in, const int* in_sizes, int n_in,
                              void* d_out, int out_size, void* d_ws, size_t ws_size,
                              hipStream_t stream) {
  const float* node_feats = (const float*)d_in[0];
  const float* edge_feats = (const float*)d_in[1];
  const int* src = (const int*)d_in[2];
  const int* dst = (const int*)d_in[3];
  const float* bn_gamma = (const float*)d_in[4];
  const float* bn_beta = (const float*)d_in[5];
  const float* gen_W = (const float*)d_in[6];
  const float* gen_b = (const float*)d_in[7];
  const float* out_W = (const float*)d_in[8];
  const float* out_b = (const float*)d_in[9];
  float* out = (float*)d_out;

  char* ws = (char*)d_ws;
  float* hvA = (float*)ws;                      // 61,440,000 B
  float* hvB = (float*)(ws + 61440000);         // 61,440,000 B
  float* statsN = (float*)(ws + 122880000);     // 4096 B (8 replicas x 128)
  float* sc = (float*)(ws + 122884096);         // 256 B
  float* sh = (float*)(ws + 122884352);         // 256 B
  int* cnt = (int*)(ws + 122884608);            // 20,000 B
  int* off = (int*)(ws + 122904608);            // 20,004 B
  int* cur = (int*)(ws + 122924612);            // 20,000 B
  int* eids = (int*)(ws + 122944612);           // 200,000 B
  int* srcs = (int*)(ws + 123144612);           // 200,000 B

  hipMemsetAsync(cnt, 0, NN * sizeof(int), stream);
  hist_kernel<<<(NE + 255) / 256, 256, 0, stream>>>(dst, cnt);
  scan_kernel<<<1, 256, 0, stream>>>(cnt, off, cur);
  scatter_kernel<<<(NE + 255) / 256, 256, 0, stream>>>(dst, src, cur, eids, srcs);

  hipMemsetAsync(statsN, 0, 1024 * sizeof(float), stream);
  bn_stats_kernel<<<C * SPLIT, 256, 0, stream>>>(node_feats, statsN);

  const float* hvPrev = node_feats;
  float* bufs[2] = {hvA, hvB};
  for (int l = 0; l < 3; l++) {
    finalize2_kernel<<<1, 64, 0, stream>>>(statsN, bn_gamma + l * C, bn_beta + l * C, sc, sh);
    if (l < 2) {
      hipMemsetAsync(statsN, 0, 1024 * sizeof(float), stream);
      float* hvNext = bufs[l & 1];
      aggregate_kernel<false><<<NN, 256, 0, stream>>>(
          hvPrev, edge_feats, srcs, eids, off, gen_W + l * C * C, gen_b + l * C,
          sc, sh, hvNext, statsN, out_W, out_b, out);
      hvPrev = hvNext;
    } else {
      aggregate_kernel<true><<<NN, 256, 0, stream>>>(
          hvPrev, edge_feats, srcs, eids, off, gen_W + l * C * C, gen_b + l * C,
          sc, sh, hvA, statsN, out_W, out_b, out);
    }
  }
}

// Round 5
// 559.234 us; speedup vs baseline: 1.2925x; 1.1296x over previous
//
#include <hip/hip_runtime.h>
#include <float.h>

#define NN 5000
#define NE 50000
#define C 64
#define CHW4 768       // 64*12*4 / 4 (float4 units per node row)
#define SPLIT 25
#define NPS 200        // 5000/25
#define MAXD 64

typedef float f32x4 __attribute__((ext_vector_type(4)));
typedef unsigned int u32x2 __attribute__((ext_vector_type(2)));

__device__ __forceinline__ unsigned int pack_bf16(float a, float b) {
  unsigned int ua = __float_as_uint(a), ub = __float_as_uint(b);
  ua = (ua + 0x7FFFu + ((ua >> 16) & 1u)) >> 16;
  ub = (ub + 0x7FFFu + ((ub >> 16) & 1u)) & 0xFFFF0000u;
  return ua | ub;
}
__device__ __forceinline__ float bf_lo(unsigned int u) { return __uint_as_float(u << 16); }
__device__ __forceinline__ float bf_hi(unsigned int u) { return __uint_as_float(u & 0xFFFF0000u); }

// ---------------- CSR build ----------------
__global__ void hist_kernel(const int* __restrict__ dst, int* __restrict__ cnt) {
  int e = blockIdx.x * 256 + threadIdx.x;
  if (e < NE) atomicAdd(&cnt[dst[e]], 1);
}

__global__ void scan_kernel(const int* __restrict__ cnt, int* __restrict__ off, int* __restrict__ cur) {
  __shared__ int tsum[256];
  int t = threadIdx.x;
  constexpr int PER = 20;
  int base = t * PER;
  int vals[PER];
  int local = 0;
#pragma unroll
  for (int i = 0; i < PER; i++) {
    int idx = base + i;
    int v = (idx < NN) ? cnt[idx] : 0;
    vals[i] = local;
    local += v;
  }
  tsum[t] = local;
  __syncthreads();
  for (int o = 1; o < 256; o <<= 1) {
    int v = (t >= o) ? tsum[t - o] : 0;
    __syncthreads();
    tsum[t] += v;
    __syncthreads();
  }
  int excl = (t == 0) ? 0 : tsum[t - 1];
#pragma unroll
  for (int i = 0; i < PER; i++) {
    int idx = base + i;
    if (idx < NN) {
      int o2 = excl + vals[i];
      off[idx] = o2;
      cur[idx] = o2;
    }
  }
  if (t == 255) off[NN] = excl + local;
}

__global__ void scatter_kernel(const int* __restrict__ dst, const int* __restrict__ src,
                               int* __restrict__ cur, int* __restrict__ eids, int* __restrict__ srcs) {
  int e = blockIdx.x * 256 + threadIdx.x;
  if (e < NE) {
    int p = atomicAdd(&cur[dst[e]], 1);
    eids[p] = e;
    srcs[p] = src[e];
  }
}

// ---------------- BatchNorm stats (layer 0 only) ----------------
__global__ void bn_stats_kernel(const float* __restrict__ hv, float* __restrict__ statsN) {
  int c = blockIdx.x / SPLIT, s = blockIdx.x % SPLIT;
  int n0 = s * NPS;
  const float4* hv4 = (const float4*)hv;
  float sum = 0.f, ss = 0.f;
  for (int i = threadIdx.x; i < NPS * 12; i += 256) {
    int n = n0 + i / 12, p = i % 12;
    float4 v = hv4[(size_t)n * CHW4 + c * 12 + p];
    sum += v.x + v.y + v.z + v.w;
    ss += v.x * v.x + v.y * v.y + v.z * v.z + v.w * v.w;
  }
  __shared__ float rs[256], rq[256];
  rs[threadIdx.x] = sum;
  rq[threadIdx.x] = ss;
  __syncthreads();
  for (int o = 128; o > 0; o >>= 1) {
    if (threadIdx.x < o) {
      rs[threadIdx.x] += rs[threadIdx.x + o];
      rq[threadIdx.x] += rq[threadIdx.x + o];
    }
    __syncthreads();
  }
  if (threadIdx.x == 0) {
    int r = blockIdx.x & 7;
    atomicAdd(&statsN[r * 128 + c], rs[0]);
    atomicAdd(&statsN[r * 128 + 64 + c], rq[0]);
  }
}

__global__ void finalize2_kernel(const float* __restrict__ statsN, const float* __restrict__ gamma,
                                 const float* __restrict__ beta, float* __restrict__ sc,
                                 float* __restrict__ sh) {
  int c = threadIdx.x;
  if (c < C) {
    float s = 0.f, q = 0.f;
#pragma unroll
    for (int r = 0; r < 8; r++) {
      s += statsN[r * 128 + c];
      q += statsN[r * 128 + 64 + c];
    }
    const float inv = 1.f / 240000.f;
    float mu = s * inv;
    float var = q * inv - mu * mu;
    float scale = gamma[c] * rsqrtf(var + 1e-5f);
    sc[c] = scale;
    sh[c] = beta[c] - mu * scale;
  }
}

// ---------------- h1 = BN+ReLU(hv) in bf16 ----------------
__global__ __launch_bounds__(256) void h1_kernel(const float* __restrict__ hv,
                                                 const float* __restrict__ sc,
                                                 const float* __restrict__ sh,
                                                 u32x2* __restrict__ h1g) {
  int idx = blockIdx.x * 256 + threadIdx.x;  // float4 index, < NN*768
  int q = idx % CHW4;
  int c = q / 12;
  float s = sc[c], b = sh[c];
  float4 v = ((const float4*)hv)[idx];
  float x0 = fmaxf(v.x * s + b, 0.f);
  float x1 = fmaxf(v.y * s + b, 0.f);
  float x2 = fmaxf(v.z * s + b, 0.f);
  float x3 = fmaxf(v.w * s + b, 0.f);
  u32x2 o;
  o.x = pack_bf16(x0, x1);
  o.y = pack_bf16(x2, x3);
  h1g[idx] = o;
}

// ---------------- Fused GENConv layer ----------------
// One block per node. Edge loop gathers bf16 h1[src]; he is fp32 in layer 0
// (converted+stored to bf16 in CSR-slot order) and bf16 stream in layers 1,2.
// Plain exp softmax (shift-invariance: max-subtraction unnecessary, m <= ~11).
template <bool FIRST, bool LAST>
__global__ __launch_bounds__(256) void aggregate_kernel(
    const float* __restrict__ hv, const float* __restrict__ he,
    const u32x2* __restrict__ h1g, u32x2* __restrict__ heb,
    const int* __restrict__ srcs, const int* __restrict__ eids, const int* __restrict__ off,
    const float* __restrict__ Wg, const float* __restrict__ bg,
    const float* __restrict__ sc, const float* __restrict__ sh,
    float* __restrict__ hvNext, float* __restrict__ statsNext,
    const float* __restrict__ oW, const float* __restrict__ ob,
    float* __restrict__ out) {
  __shared__ float Wl[4096];
  __shared__ float fl[3072];
  __shared__ float scl[64], shl[64];
  __shared__ int sS[MAXD], sE[MAXD];
  __shared__ float bsum[64], bsq[64];

  int n = blockIdx.x, t = threadIdx.x;
  for (int i = t; i < 4096; i += 256) Wl[i] = Wg[i];
  if (t < 64) {
    scl[t] = sc[t];
    shl[t] = sh[t];
    bsum[t] = 0.f;
    bsq[t] = 0.f;
  }
  __syncthreads();

  const float4* hv4 = (const float4*)hv;
  const f32x4* heV = (const f32x4*)he;

  // self h1 in fp32 (exact)
  float h1[12];
#pragma unroll
  for (int j = 0; j < 3; j++) {
    int q = t + j * 256;
    int c = q / 12;
    float s = scl[c], b = shl[c];
    float4 v = hv4[(size_t)n * CHW4 + q];
    h1[4 * j + 0] = fmaxf(v.x * s + b, 0.f);
    h1[4 * j + 1] = fmaxf(v.y * s + b, 0.f);
    h1[4 * j + 2] = fmaxf(v.z * s + b, 0.f);
    h1[4 * j + 3] = fmaxf(v.w * s + b, 0.f);
  }

  float S[12], T[12];
#pragma unroll
  for (int i = 0; i < 12; i++) {
    S[i] = 0.f;
    T[i] = 0.f;
  }

  int e0 = off[n], d = off[n + 1] - e0;
  for (int base = 0; base < d; base += MAXD) {
    int cnt = min(MAXD, d - base);
    __syncthreads();
    if (t < cnt) {
      sS[t] = srcs[e0 + base + t];
      if (FIRST) sE[t] = eids[e0 + base + t];
    }
    __syncthreads();
#pragma unroll 2
    for (int k = 0; k < cnt; k++) {
      size_t hb = (size_t)sS[k] * CHW4;
      size_t pb = (size_t)(e0 + base + k) * CHW4;  // CSR-slot position for he_bf16
#pragma unroll
      for (int j = 0; j < 3; j++) {
        int q = t + j * 256;
        u32x2 hg = h1g[hb + q];  // bf16 gather (cacheable)
        float hgf[4] = {bf_lo(hg.x), bf_hi(hg.x), bf_lo(hg.y), bf_hi(hg.y)};
        float hef[4];
        if (FIRST) {
          f32x4 b = __builtin_nontemporal_load(&heV[(size_t)sE[k] * CHW4 + q]);
          hef[0] = b.x; hef[1] = b.y; hef[2] = b.z; hef[3] = b.w;
          u32x2 o;
          o.x = pack_bf16(b.x, b.y);
          o.y = pack_bf16(b.z, b.w);
          __builtin_nontemporal_store(o, &heb[pb + q]);
        } else {
          u32x2 bb = __builtin_nontemporal_load(&heb[pb + q]);
          hef[0] = bf_lo(bb.x); hef[1] = bf_hi(bb.x); hef[2] = bf_lo(bb.y); hef[3] = bf_hi(bb.y);
        }
#pragma unroll
        for (int u = 0; u < 4; u++) {
          float m = fmaxf(hgf[u] + hef[u], 0.f) + 1e-7f;
          float e = __expf(m);  // shift-free softmax: m bounded, no overflow
          int idx = j * 4 + u;
          S[idx] += e;
          T[idx] += e * m;
        }
      }
    }
  }

  bool hasE = d > 0;
  float4* fl4 = (float4*)fl;
#pragma unroll
  for (int j = 0; j < 3; j++) {
    int q = t + j * 256, idx = 4 * j;
    float4 f;
    f.x = h1[idx + 0] + (hasE ? T[idx + 0] / S[idx + 0] : 0.f);
    f.y = h1[idx + 1] + (hasE ? T[idx + 1] / S[idx + 1] : 0.f);
    f.z = h1[idx + 2] + (hasE ? T[idx + 2] / S[idx + 2] : 0.f);
    f.w = h1[idx + 3] + (hasE ? T[idx + 3] / S[idx + 3] : 0.f);
    fl4[q] = f;
  }
  __syncthreads();

  // linear: 192 threads, each owns 4 consecutive out-channels x one h position
  int o0 = (t / 12) * 4, hbp = t % 12;
  float4 acc[4];
  if (t < 192) {
#pragma unroll
    for (int i = 0; i < 4; i++) {
      float bv = bg[o0 + i];
      acc[i] = make_float4(bv, bv, bv, bv);
    }
    const float4* w4 = (const float4*)Wl;
    int widx = o0 >> 2;
    for (int c2 = 0; c2 < 64; c2++) {
      float4 fv = fl4[c2 * 12 + hbp];
      float4 wv = w4[c2 * 16 + widx];
      acc[0].x += wv.x * fv.x; acc[0].y += wv.x * fv.y; acc[0].z += wv.x * fv.z; acc[0].w += wv.x * fv.w;
      acc[1].x += wv.y * fv.x; acc[1].y += wv.y * fv.y; acc[1].z += wv.y * fv.z; acc[1].w += wv.y * fv.w;
      acc[2].x += wv.z * fv.x; acc[2].y += wv.z * fv.y; acc[2].z += wv.z * fv.z; acc[2].w += wv.z * fv.w;
      acc[3].x += wv.w * fv.x; acc[3].y += wv.w * fv.y; acc[3].z += wv.w * fv.z; acc[3].w += wv.w * fv.w;
    }
#pragma unroll
    for (int i = 0; i < 4; i++) {
      float4 r = hv4[(size_t)n * CHW4 + (o0 + i) * 12 + hbp];
      acc[i].x += r.x; acc[i].y += r.y; acc[i].z += r.z; acc[i].w += r.w;
    }
  }

  if constexpr (!LAST) {
    if (t < 192) {
      float4* hn4 = (float4*)hvNext;
#pragma unroll
      for (int i = 0; i < 4; i++) {
        hn4[(size_t)n * CHW4 + (o0 + i) * 12 + hbp] = acc[i];
        float s4 = acc[i].x + acc[i].y + acc[i].z + acc[i].w;
        float q4 = acc[i].x * acc[i].x + acc[i].y * acc[i].y + acc[i].z * acc[i].z + acc[i].w * acc[i].w;
        atomicAdd(&bsum[o0 + i], s4);
        atomicAdd(&bsq[o0 + i], q4);
      }
    }
    __syncthreads();
    int r = n & 7;
    if (t < 64) atomicAdd(&statsNext[r * 128 + t], bsum[t]);
    else if (t < 128) atomicAdd(&statsNext[r * 128 + 64 + (t - 64)], bsq[t - 64]);
  } else {
    __syncthreads();
    if (t < 192) {
#pragma unroll
      for (int i = 0; i < 4; i++) fl4[(o0 + i) * 12 + hbp] = acc[i];
    }
    for (int i = t; i < 768; i += 256) Wl[i] = oW[i];
    __syncthreads();
    for (int i = t; i < 768; i += 256) {
      float4 v = fl4[i];
      Wl[1024 + i] = (v.x + v.y + v.z + v.w) * 0.25f;
    }
    __syncthreads();
    if (t < 144) {
      int o = t / 12, hb = t % 12;
      float bias = ob[o];
      float4 a = make_float4(bias, bias, bias, bias);
      for (int c2 = 0; c2 < 64; c2++) {
        float4 v = fl4[c2 * 12 + hb];
        float wv = Wl[c2 * 12 + o] * Wl[1024 + c2 * 12 + hb];
        a.x += wv * v.x; a.y += wv * v.y; a.z += wv * v.z; a.w += wv * v.w;
      }
      ((float4*)out)[(size_t)n * 144 + t] = a;
    }
  }
}

extern "C" void kernel_launch(void* const* d_in, const int* in_sizes, int n_in,
                              void* d_out, int out_size, void* d_ws, size_t ws_size,
                              hipStream_t stream) {
  const float* node_feats = (const float*)d_in[0];
  const float* edge_feats = (const float*)d_in[1];
  const int* src = (const int*)d_in[2];
  const int* dst = (const int*)d_in[3];
  const float* bn_gamma = (const float*)d_in[4];
  const float* bn_beta = (const float*)d_in[5];
  const float* gen_W = (const float*)d_in[6];
  const float* gen_b = (const float*)d_in[7];
  const float* out_W = (const float*)d_in[8];
  const float* out_b = (const float*)d_in[9];
  float* out = (float*)d_out;

  char* ws = (char*)d_ws;
  float* hvA = (float*)ws;                        // 61,440,000 B
  float* hvB = (float*)(ws + 61440000);           // 61,440,000 B
  u32x2* h1g = (u32x2*)(ws + 122880000);          // 30,720,000 B (bf16 h1)
  u32x2* heb = (u32x2*)(ws + 153600000);          // 307,200,000 B (bf16 he, CSR order)
  float* statsN = (float*)(ws + 460800000);       // 4096 B
  float* sc = (float*)(ws + 460804096);           // 256 B
  float* sh = (float*)(ws + 460804352);           // 256 B
  int* cnt = (int*)(ws + 460804608);              // 20,000 B
  int* off = (int*)(ws + 460824608);              // 20,004 B
  int* cur = (int*)(ws + 460844612);              // 20,000 B
  int* eids = (int*)(ws + 460864612);             // 200,000 B
  int* srcs = (int*)(ws + 461064612);             // 200,000 B

  hipMemsetAsync(cnt, 0, NN * sizeof(int), stream);
  hist_kernel<<<(NE + 255) / 256, 256, 0, stream>>>(dst, cnt);
  scan_kernel<<<1, 256, 0, stream>>>(cnt, off, cur);
  scatter_kernel<<<(NE + 255) / 256, 256, 0, stream>>>(dst, src, cur, eids, srcs);

  hipMemsetAsync(statsN, 0, 1024 * sizeof(float), stream);
  bn_stats_kernel<<<C * SPLIT, 256, 0, stream>>>(node_feats, statsN);

  const float* hvPrev = node_feats;
  float* bufs[2] = {hvA, hvB};
  for (int l = 0; l < 3; l++) {
    finalize2_kernel<<<1, 64, 0, stream>>>(statsN, bn_gamma + l * C, bn_beta + l * C, sc, sh);
    h1_kernel<<<NN * CHW4 / 256, 256, 0, stream>>>(hvPrev, sc, sh, h1g);
    if (l == 0) {
      hipMemsetAsync(statsN, 0, 1024 * sizeof(float), stream);
      aggregate_kernel<true, false><<<NN, 256, 0, stream>>>(
          hvPrev, edge_feats, h1g, heb, srcs, eids, off, gen_W, gen_b,
          sc, sh, bufs[0], statsN, out_W, out_b, out);
      hvPrev = bufs[0];
    } else if (l == 1) {
      hipMemsetAsync(statsN, 0, 1024 * sizeof(float), stream);
      aggregate_kernel<false, false><<<NN, 256, 0, stream>>>(
          hvPrev, edge_feats, h1g, heb, srcs, eids, off, gen_W + C * C, gen_b + C,
          sc, sh, bufs[1], statsN, out_W, out_b, out);
      hvPrev = bufs[1];
    } else {
      aggregate_kernel<false, true><<<NN, 256, 0, stream>>>(
          hvPrev, edge_feats, h1g, heb, srcs, eids, off, gen_W + 2 * C * C, gen_b + 2 * C,
          sc, sh, bufs[0], statsN, out_W, out_b, out);
    }
  }
}